// Round 2
// baseline (2660.203 us; speedup 1.0000x reference)
//
#include <hip/hip_runtime.h>
#include <math.h>

#define DMODEL 1024
#define NHEAD  16
#define DHEAD  64
#define BATCH  2
#define SEQ    2048
#define MROWS  (BATCH * SEQ)   // 4096

// ---------------------------------------------------------------------------
// GEMM: Y[m][n] = sum_k X[m][k] * W[n][k]   (X: [M,K] fp32, W: [N,K] fp32)
// Writes result into [b,h,s,dh] fp32 layout: dst[((b*H+h)*S+s)*64+dh]
// BM=BN=64, BK=16, 256 threads, 4x4 acc per thread.
// ---------------------------------------------------------------------------
__global__ __launch_bounds__(256)
void gemm_proj_bhsd(const float* __restrict__ X,
                    const float* __restrict__ W,
                    float* __restrict__ dst) {
    __shared__ float As[16][65];
    __shared__ float Bs[16][65];
    const int tid = threadIdx.x;
    const int m0 = blockIdx.y * 64;
    const int n0 = blockIdx.x * 64;
    float acc[4][4] = {};
    const int r  = tid >> 2;         // 0..63
    const int c0 = (tid & 3) * 4;    // 0,4,8,12
    const int tm = (tid >> 4) * 4;
    const int tn = (tid & 15) * 4;
    for (int k0 = 0; k0 < DMODEL; k0 += 16) {
        const float4 xv = *reinterpret_cast<const float4*>(
            X + (size_t)(m0 + r) * DMODEL + k0 + c0);
        const float4 wv = *reinterpret_cast<const float4*>(
            W + (size_t)(n0 + r) * DMODEL + k0 + c0);
        As[c0 + 0][r] = xv.x; As[c0 + 1][r] = xv.y;
        As[c0 + 2][r] = xv.z; As[c0 + 3][r] = xv.w;
        Bs[c0 + 0][r] = wv.x; Bs[c0 + 1][r] = wv.y;
        Bs[c0 + 2][r] = wv.z; Bs[c0 + 3][r] = wv.w;
        __syncthreads();
        #pragma unroll
        for (int kk = 0; kk < 16; kk++) {
            float a[4], b[4];
            #pragma unroll
            for (int i = 0; i < 4; i++) a[i] = As[kk][tm + i];
            #pragma unroll
            for (int j = 0; j < 4; j++) b[j] = Bs[kk][tn + j];
            #pragma unroll
            for (int i = 0; i < 4; i++)
                #pragma unroll
                for (int j = 0; j < 4; j++) acc[i][j] += a[i] * b[j];
        }
        __syncthreads();
    }
    #pragma unroll
    for (int i = 0; i < 4; i++) {
        const int m = m0 + tm + i;
        const int bb = m >> 11;          // m / SEQ
        const int ss = m & (SEQ - 1);
        #pragma unroll
        for (int j = 0; j < 4; j++) {
            const int n  = n0 + tn + j;
            const int h  = n >> 6;
            const int dh = n & 63;
            dst[(((size_t)(bb * NHEAD + h)) * SEQ + ss) * DHEAD + dh] = acc[i][j];
        }
    }
}

// ---------------------------------------------------------------------------
// RoPE (interleaved pairs) applied in-place to q and k ([b,h,s,dh] fp32).
// ---------------------------------------------------------------------------
__global__ __launch_bounds__(256)
void rope_kernel(float* __restrict__ q, float* __restrict__ k,
                 const int* __restrict__ pos) {
    const int idx = blockIdx.x * blockDim.x + threadIdx.x;
    const int total = BATCH * NHEAD * SEQ * (DHEAD / 2);
    if (idx >= total) return;
    const int i  = idx & 31;                 // pair index 0..31
    const int s  = (idx >> 5) & (SEQ - 1);
    const int bh = idx >> 16;                // idx / (32*2048)
    const float p = (float)pos[s];
    const float freq = p * powf(10000.0f, -(float)(2 * i) / (float)DHEAD);
    float sn, cs;
    sincosf(freq, &sn, &cs);
    const size_t base = (((size_t)bh * SEQ + s) * DHEAD) + 2 * i;
    float x1 = q[base], x2 = q[base + 1];
    q[base]     = x1 * cs - x2 * sn;
    q[base + 1] = x1 * sn + x2 * cs;
    x1 = k[base]; x2 = k[base + 1];
    k[base]     = x1 * cs - x2 * sn;
    k[base + 1] = x1 * sn + x2 * cs;
}

// ---------------------------------------------------------------------------
// Causal attention, flash-style. One wave per query row, 4 rows per block.
// K/V tiles of 64 staged in LDS. Online softmax in registers + shuffles.
// ---------------------------------------------------------------------------
__global__ __launch_bounds__(256)
void attn_kernel(const float* __restrict__ qb, const float* __restrict__ kb,
                 const float* __restrict__ vb, float* __restrict__ ob) {
    __shared__ float Kt[64][65];   // padded: dot-product read is row-per-lane
    __shared__ float Vt[64][64];   // read col-per-lane: conflict-free
    __shared__ float Qs[4][64];
    const int bh = blockIdx.y;
    const int r0 = blockIdx.x * 4;
    const int tid = threadIdx.x;
    const int w = tid >> 6;
    const int lane = tid & 63;
    const int row = r0 + w;
    const size_t base = (size_t)bh * SEQ * DHEAD;

    Qs[w][lane] = qb[base + (size_t)row * DHEAD + lane];

    float m = -INFINITY, l = 0.f, o = 0.f;
    const int ntiles = (r0 + 3) / 64 + 1;
    const int kr = tid >> 2;
    const int kc = (tid & 3) * 16;
    for (int t = 0; t < ntiles; t++) {
        __syncthreads();   // Qs ready (iter 0); prior tile reads done (iter>0)
        {
            const float* kp = kb + base + (size_t)(t * 64 + kr) * DHEAD + kc;
            const float* vp = vb + base + (size_t)(t * 64 + kr) * DHEAD + kc;
            #pragma unroll
            for (int i = 0; i < 16; i += 4) {
                const float4 kv = *reinterpret_cast<const float4*>(kp + i);
                const float4 vv = *reinterpret_cast<const float4*>(vp + i);
                Kt[kr][kc + i + 0] = kv.x; Kt[kr][kc + i + 1] = kv.y;
                Kt[kr][kc + i + 2] = kv.z; Kt[kr][kc + i + 3] = kv.w;
                Vt[kr][kc + i + 0] = vv.x; Vt[kr][kc + i + 1] = vv.y;
                Vt[kr][kc + i + 2] = vv.z; Vt[kr][kc + i + 3] = vv.w;
            }
        }
        __syncthreads();
        if (t * 64 <= row) {
            const int kg = t * 64 + lane;
            float s;
            if (kg <= row) {
                s = 0.f;
                #pragma unroll
                for (int d = 0; d < 64; d++) s += Qs[w][d] * Kt[lane][d];
                s *= 0.125f;   // 1/sqrt(64)
            } else {
                s = -INFINITY;
            }
            float mt = s;
            #pragma unroll
            for (int off = 32; off; off >>= 1) mt = fmaxf(mt, __shfl_xor(mt, off, 64));
            const float m_new = fmaxf(m, mt);
            const float alpha = __expf(m - m_new);   // m=-inf on first tile -> 0
            const float p = __expf(s - m_new);       // s=-inf -> 0
            float sum = p;
            #pragma unroll
            for (int off = 32; off; off >>= 1) sum += __shfl_xor(sum, off, 64);
            l = l * alpha + sum;
            o = o * alpha;
            #pragma unroll
            for (int kk = 0; kk < 64; kk++) {
                const float pk = __shfl(p, kk, 64);
                o += pk * Vt[kk][lane];
            }
            m = m_new;
        }
    }
    ob[base + (size_t)row * DHEAD + lane] = o / l;
}

// ---------------------------------------------------------------------------
// Output GEMM: out[m][n] = sum_k O'[m][k] * Wo[n][k], O' read from [b,h,s,dh].
// ---------------------------------------------------------------------------
__global__ __launch_bounds__(256)
void gemm_out(const float* __restrict__ O, const float* __restrict__ W,
              float* __restrict__ Y) {
    __shared__ float As[16][65];
    __shared__ float Bs[16][65];
    const int tid = threadIdx.x;
    const int m0 = blockIdx.y * 64;
    const int n0 = blockIdx.x * 64;
    float acc[4][4] = {};
    const int r  = tid >> 2;
    const int c0 = (tid & 3) * 4;
    const int tm = (tid >> 4) * 4;
    const int tn = (tid & 15) * 4;
    const int m  = m0 + r;
    const int bb = m >> 11;
    const int ss = m & (SEQ - 1);
    for (int k0 = 0; k0 < DMODEL; k0 += 16) {
        {
            const int kbase = k0 + c0;
            const int h = kbase >> 6;         // same head for all 4 (4|64)
            const int dh = kbase & 63;
            const float4 ov = *reinterpret_cast<const float4*>(
                O + (((size_t)(bb * NHEAD + h)) * SEQ + ss) * DHEAD + dh);
            As[c0 + 0][r] = ov.x; As[c0 + 1][r] = ov.y;
            As[c0 + 2][r] = ov.z; As[c0 + 3][r] = ov.w;
            const float4 wv = *reinterpret_cast<const float4*>(
                W + (size_t)(n0 + r) * DMODEL + k0 + c0);
            Bs[c0 + 0][r] = wv.x; Bs[c0 + 1][r] = wv.y;
            Bs[c0 + 2][r] = wv.z; Bs[c0 + 3][r] = wv.w;
        }
        __syncthreads();
        #pragma unroll
        for (int kk = 0; kk < 16; kk++) {
            float a[4], b[4];
            #pragma unroll
            for (int i = 0; i < 4; i++) a[i] = As[kk][tm + i];
            #pragma unroll
            for (int j = 0; j < 4; j++) b[j] = Bs[kk][tn + j];
            #pragma unroll
            for (int i = 0; i < 4; i++)
                #pragma unroll
                for (int j = 0; j < 4; j++) acc[i][j] += a[i] * b[j];
        }
        __syncthreads();
    }
    #pragma unroll
    for (int i = 0; i < 4; i++)
        #pragma unroll
        for (int j = 0; j < 4; j++)
            Y[(size_t)(m0 + tm + i) * DMODEL + (n0 + tn + j)] = acc[i][j];
}

// ---------------------------------------------------------------------------
extern "C" void kernel_launch(void* const* d_in, const int* in_sizes, int n_in,
                              void* d_out, int out_size, void* d_ws, size_t ws_size,
                              hipStream_t stream) {
    const float* x  = (const float*)d_in[0];
    const float* Wq = (const float*)d_in[1];
    const float* Wk = (const float*)d_in[2];
    const float* Wv = (const float*)d_in[3];
    const float* Wo = (const float*)d_in[4];
    const int* pos = (const int*)d_in[5];

    const size_t TEN = (size_t)MROWS * DMODEL;   // 4M floats
    float* q = (float*)d_ws;
    float* k = q + TEN;
    float* v = k + TEN;
    float* o = v + TEN;

    dim3 blk(256);
    dim3 gproj(DMODEL / 64, MROWS / 64);   // (16, 64)
    gemm_proj_bhsd<<<gproj, blk, 0, stream>>>(x, Wq, q);
    gemm_proj_bhsd<<<gproj, blk, 0, stream>>>(x, Wk, k);
    gemm_proj_bhsd<<<gproj, blk, 0, stream>>>(x, Wv, v);

    const int npairs = BATCH * NHEAD * SEQ * (DHEAD / 2);
    rope_kernel<<<(npairs + 255) / 256, blk, 0, stream>>>(q, k, pos);

    dim3 gattn(SEQ / 4, BATCH * NHEAD);    // (512, 32)
    attn_kernel<<<gattn, blk, 0, stream>>>(q, k, v, o);

    gemm_out<<<gproj, blk, 0, stream>>>(o, Wo, (float*)d_out);
}

// Round 3
// 892.129 us; speedup vs baseline: 2.9819x; 2.9819x over previous
//
#include <hip/hip_runtime.h>
#include <hip/hip_bf16.h>
#include <math.h>

#define DMODEL 1024
#define NHEAD  16
#define DHEAD  64
#define BATCH  2
#define SEQ    2048
#define MROWS  (BATCH * SEQ)   // 4096

typedef __attribute__((ext_vector_type(8))) __bf16 bf16x8;
typedef __attribute__((ext_vector_type(4))) float  f32x4;

__device__ inline void store_val(float* p, float v)          { *p = v; }
__device__ inline void store_val(__hip_bfloat16* p, float v) { *p = __float2bfloat16(v); }

// ---------------------------------------------------------------------------
// GEMM: Y[m][n] = sum_k X[m][k] * W[n][k]; writes [b,h,s,dh] layout, dtype T.
// ---------------------------------------------------------------------------
template <typename T>
__global__ __launch_bounds__(256)
void gemm_proj_bhsd(const float* __restrict__ X,
                    const float* __restrict__ W,
                    T* __restrict__ dst) {
    __shared__ float As[16][65];
    __shared__ float Bs[16][65];
    const int tid = threadIdx.x;
    const int m0 = blockIdx.y * 64;
    const int n0 = blockIdx.x * 64;
    float acc[4][4] = {};
    const int r  = tid >> 2;
    const int c0 = (tid & 3) * 4;
    const int tm = (tid >> 4) * 4;
    const int tn = (tid & 15) * 4;
    for (int k0 = 0; k0 < DMODEL; k0 += 16) {
        const float4 xv = *reinterpret_cast<const float4*>(
            X + (size_t)(m0 + r) * DMODEL + k0 + c0);
        const float4 wv = *reinterpret_cast<const float4*>(
            W + (size_t)(n0 + r) * DMODEL + k0 + c0);
        As[c0 + 0][r] = xv.x; As[c0 + 1][r] = xv.y;
        As[c0 + 2][r] = xv.z; As[c0 + 3][r] = xv.w;
        Bs[c0 + 0][r] = wv.x; Bs[c0 + 1][r] = wv.y;
        Bs[c0 + 2][r] = wv.z; Bs[c0 + 3][r] = wv.w;
        __syncthreads();
        #pragma unroll
        for (int kk = 0; kk < 16; kk++) {
            float a[4], b[4];
            #pragma unroll
            for (int i = 0; i < 4; i++) a[i] = As[kk][tm + i];
            #pragma unroll
            for (int j = 0; j < 4; j++) b[j] = Bs[kk][tn + j];
            #pragma unroll
            for (int i = 0; i < 4; i++)
                #pragma unroll
                for (int j = 0; j < 4; j++) acc[i][j] += a[i] * b[j];
        }
        __syncthreads();
    }
    #pragma unroll
    for (int i = 0; i < 4; i++) {
        const int m = m0 + tm + i;
        const int bb = m >> 11;
        const int ss = m & (SEQ - 1);
        #pragma unroll
        for (int j = 0; j < 4; j++) {
            const int n  = n0 + tn + j;
            const int h  = n >> 6;
            const int dh = n & 63;
            store_val(&dst[(((size_t)(bb * NHEAD + h)) * SEQ + ss) * DHEAD + dh],
                      acc[i][j]);
        }
    }
}

// ---------------------------------------------------------------------------
// RoPE in-place on bf16 q,k ([b,h,s,dh]).
// ---------------------------------------------------------------------------
__global__ __launch_bounds__(256)
void rope_bf16(__hip_bfloat16* __restrict__ q, __hip_bfloat16* __restrict__ k,
               const int* __restrict__ pos) {
    const int idx = blockIdx.x * blockDim.x + threadIdx.x;
    const int total = BATCH * NHEAD * SEQ * (DHEAD / 2);
    if (idx >= total) return;
    const int i  = idx & 31;
    const int s  = (idx >> 5) & (SEQ - 1);
    const int bh = idx >> 16;
    const float p = (float)pos[s];
    const float freq = p * powf(10000.0f, -(float)(2 * i) / (float)DHEAD);
    float sn, cs;
    sincosf(freq, &sn, &cs);
    const size_t base = (((size_t)bh * SEQ + s) * DHEAD) + 2 * i;
    float x1 = __bfloat162float(q[base]), x2 = __bfloat162float(q[base + 1]);
    q[base]     = __float2bfloat16(x1 * cs - x2 * sn);
    q[base + 1] = __float2bfloat16(x1 * sn + x2 * cs);
    x1 = __bfloat162float(k[base]); x2 = __bfloat162float(k[base + 1]);
    k[base]     = __float2bfloat16(x1 * cs - x2 * sn);
    k[base + 1] = __float2bfloat16(x1 * sn + x2 * cs);
}

// ---------------------------------------------------------------------------
// MFMA flash attention. Block = 64 q-rows x one (b,h); 4 waves x 16 q-rows.
// K/V tiles of 64 keys staged to LDS as bf16 (V transposed). Online softmax.
// mfma_f32_16x16x32_bf16: A/B frag = [m|n = lane&15][k = (lane>>4)*8 + j],
// C/D: col = lane&15, row = (lane>>4)*4 + reg.
// ---------------------------------------------------------------------------
__global__ __launch_bounds__(256)
void attn_mfma(const __hip_bfloat16* __restrict__ qb,
               const __hip_bfloat16* __restrict__ kb,
               const __hip_bfloat16* __restrict__ vb,
               float* __restrict__ ob) {
    __shared__ ushort Ks[64][72];      // [key][d]   bf16, +8 pad (16B-aligned rows)
    __shared__ ushort Vt[64][72];      // [d][key]   bf16 transposed
    __shared__ float  Ps[4][16][68];   // wave-private P tile [q][key], f32

    const int bh   = blockIdx.y;
    const int qt   = blockIdx.x;
    const int tid  = threadIdx.x;
    const int w    = tid >> 6;
    const int lane = tid & 63;
    const int l16  = lane & 15;
    const int quad = lane >> 4;
    const size_t base = (size_t)bh * SEQ * DHEAD;

    // Q A-frags: held in registers for the whole block
    const int qrow = qt * 64 + w * 16 + l16;
    bf16x8 qa[2];
    qa[0] = *reinterpret_cast<const bf16x8*>(qb + base + (size_t)qrow * DHEAD + quad * 8);
    qa[1] = *reinterpret_cast<const bf16x8*>(qb + base + (size_t)qrow * DHEAD + 32 + quad * 8);

    f32x4 oacc[4];
    #pragma unroll
    for (int s = 0; s < 4; s++) oacc[s] = (f32x4){0.f, 0.f, 0.f, 0.f};
    float mrow[4] = {-INFINITY, -INFINITY, -INFINITY, -INFINITY};
    float lrow[4] = {0.f, 0.f, 0.f, 0.f};

    const int key_s = tid & 63;   // staging: each thread owns one key row,
    const int dgrp  = tid >> 6;   // 16 d-elements starting at dgrp*16

    for (int t = 0; t <= qt; ++t) {
        __syncthreads();   // previous tile's LDS reads complete
        {
            const __hip_bfloat16* kp = kb + base + (size_t)(t * 64 + key_s) * DHEAD + dgrp * 16;
            const uint4 k0 = *reinterpret_cast<const uint4*>(kp);
            const uint4 k1 = *reinterpret_cast<const uint4*>(kp + 8);
            *reinterpret_cast<uint4*>(&Ks[key_s][dgrp * 16])     = k0;
            *reinterpret_cast<uint4*>(&Ks[key_s][dgrp * 16 + 8]) = k1;
            const __hip_bfloat16* vp = vb + base + (size_t)(t * 64 + key_s) * DHEAD + dgrp * 16;
            const uint4 v0 = *reinterpret_cast<const uint4*>(vp);
            const uint4 v1 = *reinterpret_cast<const uint4*>(vp + 8);
            const ushort* ve0 = reinterpret_cast<const ushort*>(&v0);
            const ushort* ve1 = reinterpret_cast<const ushort*>(&v1);
            #pragma unroll
            for (int i = 0; i < 8; i++) Vt[dgrp * 16 + i][key_s] = ve0[i];
            #pragma unroll
            for (int i = 0; i < 8; i++) Vt[dgrp * 16 + 8 + i][key_s] = ve1[i];
        }
        __syncthreads();

        // ---- S = Q K^T (16 q-rows x 64 keys per wave) ----
        f32x4 sacc[4];
        #pragma unroll
        for (int s = 0; s < 4; s++) sacc[s] = (f32x4){0.f, 0.f, 0.f, 0.f};
        #pragma unroll
        for (int half = 0; half < 2; half++) {
            #pragma unroll
            for (int sub = 0; sub < 4; sub++) {
                const bf16x8 bk = *reinterpret_cast<const bf16x8*>(
                    &Ks[sub * 16 + l16][half * 32 + quad * 8]);
                sacc[sub] = __builtin_amdgcn_mfma_f32_16x16x32_bf16(
                    qa[half], bk, sacc[sub], 0, 0, 0);
            }
        }

        // ---- online softmax ----
        const bool diag = (t == qt);
        float p[4][4];      // [sub][r]
        float tmax[4], tsum[4];
        #pragma unroll
        for (int r = 0; r < 4; r++) {
            float mx = -INFINITY;
            #pragma unroll
            for (int sub = 0; sub < 4; sub++) {
                float s = sacc[sub][r] * 0.125f;   // 1/sqrt(64)
                if (diag && (sub * 16 + l16 > w * 16 + quad * 4 + r)) s = -INFINITY;
                p[sub][r] = s;
                mx = fmaxf(mx, s);
            }
            tmax[r] = mx;
        }
        #pragma unroll
        for (int off = 1; off < 16; off <<= 1)
            #pragma unroll
            for (int r = 0; r < 4; r++)
                tmax[r] = fmaxf(tmax[r], __shfl_xor(tmax[r], off, 64));
        #pragma unroll
        for (int r = 0; r < 4; r++) {
            const float m_new = fmaxf(mrow[r], tmax[r]);
            const float alpha = __expf(mrow[r] - m_new);   // 0 on first tile
            mrow[r] = m_new;
            float sum = 0.f;
            #pragma unroll
            for (int sub = 0; sub < 4; sub++) {
                const float e = __expf(p[sub][r] - m_new);
                p[sub][r] = e;
                sum += e;
            }
            tsum[r] = sum;
            lrow[r] *= alpha;
            #pragma unroll
            for (int sub = 0; sub < 4; sub++) oacc[sub][r] *= alpha;
        }
        #pragma unroll
        for (int off = 1; off < 16; off <<= 1)
            #pragma unroll
            for (int r = 0; r < 4; r++)
                tsum[r] += __shfl_xor(tsum[r], off, 64);
        #pragma unroll
        for (int r = 0; r < 4; r++) lrow[r] += tsum[r];

        // ---- P: C-layout -> LDS -> A-frag (wave-private, no barrier) ----
        #pragma unroll
        for (int sub = 0; sub < 4; sub++)
            #pragma unroll
            for (int r = 0; r < 4; r++)
                Ps[w][quad * 4 + r][sub * 16 + l16] = p[sub][r];
        bf16x8 pa[2];
        #pragma unroll
        for (int half = 0; half < 2; half++) {
            const float* pp = &Ps[w][l16][half * 32 + quad * 8];
            const f32x4 f0 = *reinterpret_cast<const f32x4*>(pp);
            const f32x4 f1 = *reinterpret_cast<const f32x4*>(pp + 4);
            bf16x8 tb;
            #pragma unroll
            for (int j = 0; j < 4; j++) {
                tb[j]     = (__bf16)f0[j];
                tb[4 + j] = (__bf16)f1[j];
            }
            pa[half] = tb;
        }

        // ---- O += P V ----
        #pragma unroll
        for (int half = 0; half < 2; half++) {
            #pragma unroll
            for (int sub = 0; sub < 4; sub++) {
                const bf16x8 bv = *reinterpret_cast<const bf16x8*>(
                    &Vt[sub * 16 + l16][half * 32 + quad * 8]);
                oacc[sub] = __builtin_amdgcn_mfma_f32_16x16x32_bf16(
                    pa[half], bv, oacc[sub], 0, 0, 0);
            }
        }
    }

    // epilogue: O / l
    #pragma unroll
    for (int sub = 0; sub < 4; sub++) {
        #pragma unroll
        for (int r = 0; r < 4; r++) {
            const int q = qt * 64 + w * 16 + quad * 4 + r;
            ob[base + (size_t)q * DHEAD + sub * 16 + l16] = oacc[sub][r] / lrow[r];
        }
    }
}

// ---------------------------------------------------------------------------
// Output GEMM: out[m][n] = sum_k O'[m][k] * Wo[n][k], O' read from [b,h,s,dh].
// ---------------------------------------------------------------------------
__global__ __launch_bounds__(256)
void gemm_out(const float* __restrict__ O, const float* __restrict__ W,
              float* __restrict__ Y) {
    __shared__ float As[16][65];
    __shared__ float Bs[16][65];
    const int tid = threadIdx.x;
    const int m0 = blockIdx.y * 64;
    const int n0 = blockIdx.x * 64;
    float acc[4][4] = {};
    const int r  = tid >> 2;
    const int c0 = (tid & 3) * 4;
    const int tm = (tid >> 4) * 4;
    const int tn = (tid & 15) * 4;
    const int m  = m0 + r;
    const int bb = m >> 11;
    const int ss = m & (SEQ - 1);
    for (int k0 = 0; k0 < DMODEL; k0 += 16) {
        {
            const int kbase = k0 + c0;
            const int h = kbase >> 6;
            const int dh = kbase & 63;
            const float4 ov = *reinterpret_cast<const float4*>(
                O + (((size_t)(bb * NHEAD + h)) * SEQ + ss) * DHEAD + dh);
            As[c0 + 0][r] = ov.x; As[c0 + 1][r] = ov.y;
            As[c0 + 2][r] = ov.z; As[c0 + 3][r] = ov.w;
            const float4 wv = *reinterpret_cast<const float4*>(
                W + (size_t)(n0 + r) * DMODEL + k0 + c0);
            Bs[c0 + 0][r] = wv.x; Bs[c0 + 1][r] = wv.y;
            Bs[c0 + 2][r] = wv.z; Bs[c0 + 3][r] = wv.w;
        }
        __syncthreads();
        #pragma unroll
        for (int kk = 0; kk < 16; kk++) {
            float a[4], b[4];
            #pragma unroll
            for (int i = 0; i < 4; i++) a[i] = As[kk][tm + i];
            #pragma unroll
            for (int j = 0; j < 4; j++) b[j] = Bs[kk][tn + j];
            #pragma unroll
            for (int i = 0; i < 4; i++)
                #pragma unroll
                for (int j = 0; j < 4; j++) acc[i][j] += a[i] * b[j];
        }
        __syncthreads();
    }
    #pragma unroll
    for (int i = 0; i < 4; i++)
        #pragma unroll
        for (int j = 0; j < 4; j++)
            Y[(size_t)(m0 + tm + i) * DMODEL + (n0 + tn + j)] = acc[i][j];
}

// ---------------------------------------------------------------------------
extern "C" void kernel_launch(void* const* d_in, const int* in_sizes, int n_in,
                              void* d_out, int out_size, void* d_ws, size_t ws_size,
                              hipStream_t stream) {
    const float* x  = (const float*)d_in[0];
    const float* Wq = (const float*)d_in[1];
    const float* Wk = (const float*)d_in[2];
    const float* Wv = (const float*)d_in[3];
    const float* Wo = (const float*)d_in[4];
    const int* pos = (const int*)d_in[5];

    const size_t TEN = (size_t)MROWS * DMODEL;   // 4M elements
    __hip_bfloat16* qb = (__hip_bfloat16*)d_ws;              //  8 MB
    __hip_bfloat16* kb = qb + TEN;                           //  8 MB
    __hip_bfloat16* vb = kb + TEN;                           //  8 MB
    float* o = (float*)(vb + TEN);                           // 16 MB

    dim3 blk(256);
    dim3 gproj(DMODEL / 64, MROWS / 64);   // (16, 64)
    gemm_proj_bhsd<__hip_bfloat16><<<gproj, blk, 0, stream>>>(x, Wq, qb);
    gemm_proj_bhsd<__hip_bfloat16><<<gproj, blk, 0, stream>>>(x, Wk, kb);
    gemm_proj_bhsd<__hip_bfloat16><<<gproj, blk, 0, stream>>>(x, Wv, vb);

    const int npairs = BATCH * NHEAD * SEQ * (DHEAD / 2);
    rope_bf16<<<(npairs + 255) / 256, blk, 0, stream>>>(qb, kb, pos);

    dim3 gattn(SEQ / 64, BATCH * NHEAD);   // (32, 32)
    attn_mfma<<<gattn, blk, 0, stream>>>(qb, kb, vb, o);

    gemm_out<<<gproj, blk, 0, stream>>>(o, Wo, (float*)d_out);
}

// Round 4
// 328.345 us; speedup vs baseline: 8.1018x; 2.7170x over previous
//
#include <hip/hip_runtime.h>
#include <hip/hip_bf16.h>
#include <math.h>

#define DMODEL 1024
#define NHEAD  16
#define DHEAD  64
#define BATCH  2
#define SEQ    2048
#define MROWS  (BATCH * SEQ)   // 4096

typedef __attribute__((ext_vector_type(8))) __bf16 bf16x8;
typedef __attribute__((ext_vector_type(4))) float  f32x4;

// async global->LDS, 16 B per lane. LDS dest must be wave-uniform base + lane*16.
__device__ __forceinline__ void load16_lds(const ushort* g, ushort* l) {
    __builtin_amdgcn_global_load_lds(
        (const __attribute__((address_space(1))) unsigned int*)g,
        (__attribute__((address_space(3))) unsigned int*)l, 16, 0, 0);
}

// ---------------------------------------------------------------------------
// fp32 -> bf16 cast, 8 elem/thread
// ---------------------------------------------------------------------------
__global__ __launch_bounds__(256)
void cast_f32_bf16(const float* __restrict__ s, ushort* __restrict__ d, int n) {
    const int i = (blockIdx.x * 256 + threadIdx.x) * 8;
    if (i >= n) return;
    const f32x4 a = *reinterpret_cast<const f32x4*>(s + i);
    const f32x4 b = *reinterpret_cast<const f32x4*>(s + i + 4);
    bf16x8 o;
    #pragma unroll
    for (int j = 0; j < 4; j++) { o[j] = (__bf16)a[j]; o[4 + j] = (__bf16)b[j]; }
    *reinterpret_cast<bf16x8*>(d + i) = o;
}

// ---------------------------------------------------------------------------
// MFMA GEMM (m97 structure): C[m][n] = sum_k A[m][k] * B[n][k], bf16 in.
// 128x128 tile, BK=32, 4 waves each 64x64 (4x4 of 16x16x32), fp32 accum.
// AMODE 0: A row-major [M,DMODEL].  AMODE 1: A in [b,h,s,dh] (k=(h,dh)).
// OMODE 0: store bf16 to [b,h,s,dh].  OMODE 1: store f32 row-major [M,DMODEL].
// ---------------------------------------------------------------------------
template <int AMODE, int OMODE>
__global__ __launch_bounds__(256)
void gemm_bt(const ushort* __restrict__ A, const ushort* __restrict__ B,
             void* __restrict__ C) {
    __shared__ __align__(16) ushort As[128 * 32];   // unpadded: global_load_lds order
    __shared__ __align__(16) ushort Bs[128 * 32];
    const int tid  = threadIdx.x;
    const int m0   = blockIdx.y * 128;
    const int n0   = blockIdx.x * 128;
    const int lane = tid & 63;
    const int w    = tid >> 6;
    const int l16  = lane & 15;
    const int quad = lane >> 4;
    const int wm   = (w >> 1) * 64;
    const int wn   = (w & 1) * 64;

    const int srow = tid >> 2;        // 0..63 (plus +64 second half)
    const int scol = (tid & 3) * 8;   // bf16 elem offset within K-tile

    f32x4 acc[4][4];
    #pragma unroll
    for (int i = 0; i < 4; i++)
        #pragma unroll
        for (int j = 0; j < 4; j++) acc[i][j] = (f32x4){0.f, 0.f, 0.f, 0.f};

    for (int k0 = 0; k0 < DMODEL; k0 += 32) {
        __syncthreads();   // previous iteration's ds_reads complete
        #pragma unroll
        for (int half = 0; half < 2; half++) {
            const int row = srow + half * 64;
            const ushort* ga;
            if (AMODE == 0) {
                ga = A + (size_t)(m0 + row) * DMODEL + k0 + scol;
            } else {
                const int m  = m0 + row;
                const int bb = m >> 11;
                const int ss = m & (SEQ - 1);
                const int kk = k0 + scol;
                const int h  = kk >> 6;
                const int dh = kk & 63;
                ga = A + (((size_t)(bb * NHEAD + h)) * SEQ + ss) * DHEAD + dh;
            }
            load16_lds(ga, &As[row * 32 + scol]);
            load16_lds(B + (size_t)(n0 + row) * DMODEL + k0 + scol,
                       &Bs[row * 32 + scol]);
        }
        __syncthreads();   // barrier drains vmcnt: tiles landed

        bf16x8 af[4], bfr[4];
        #pragma unroll
        for (int s = 0; s < 4; s++)
            af[s] = *reinterpret_cast<const bf16x8*>(
                &As[(wm + s * 16 + l16) * 32 + quad * 8]);
        #pragma unroll
        for (int s = 0; s < 4; s++)
            bfr[s] = *reinterpret_cast<const bf16x8*>(
                &Bs[(wn + s * 16 + l16) * 32 + quad * 8]);
        #pragma unroll
        for (int i = 0; i < 4; i++)
            #pragma unroll
            for (int j = 0; j < 4; j++)
                acc[i][j] = __builtin_amdgcn_mfma_f32_16x16x32_bf16(
                    af[i], bfr[j], acc[i][j], 0, 0, 0);
    }

    // epilogue: C/D layout row = quad*4 + r, col = l16
    if (OMODE == 0) {
        __hip_bfloat16* D = (__hip_bfloat16*)C;
        #pragma unroll
        for (int i = 0; i < 4; i++) {
            #pragma unroll
            for (int r = 0; r < 4; r++) {
                const int m  = m0 + wm + i * 16 + quad * 4 + r;
                const int bb = m >> 11;
                const int ss = m & (SEQ - 1);
                #pragma unroll
                for (int j = 0; j < 4; j++) {
                    const int n  = n0 + wn + j * 16 + l16;
                    const int h  = n >> 6;
                    const int dh = n & 63;
                    D[(((size_t)(bb * NHEAD + h)) * SEQ + ss) * DHEAD + dh] =
                        __float2bfloat16(acc[i][j][r]);
                }
            }
        }
    } else {
        float* D = (float*)C;
        #pragma unroll
        for (int i = 0; i < 4; i++)
            #pragma unroll
            for (int r = 0; r < 4; r++) {
                const int m = m0 + wm + i * 16 + quad * 4 + r;
                #pragma unroll
                for (int j = 0; j < 4; j++)
                    D[(size_t)m * DMODEL + n0 + wn + j * 16 + l16] = acc[i][j][r];
            }
    }
}

// ---------------------------------------------------------------------------
// RoPE in-place on bf16 q,k ([b,h,s,dh]).
// ---------------------------------------------------------------------------
__global__ __launch_bounds__(256)
void rope_bf16(__hip_bfloat16* __restrict__ q, __hip_bfloat16* __restrict__ k,
               const int* __restrict__ pos) {
    const int idx = blockIdx.x * blockDim.x + threadIdx.x;
    const int total = BATCH * NHEAD * SEQ * (DHEAD / 2);
    if (idx >= total) return;
    const int i  = idx & 31;
    const int s  = (idx >> 5) & (SEQ - 1);
    const int bh = idx >> 16;
    const float p = (float)pos[s];
    const float freq = p * powf(10000.0f, -(float)(2 * i) / (float)DHEAD);
    float sn, cs;
    sincosf(freq, &sn, &cs);
    const size_t base = (((size_t)bh * SEQ + s) * DHEAD) + 2 * i;
    float x1 = __bfloat162float(q[base]), x2 = __bfloat162float(q[base + 1]);
    q[base]     = __float2bfloat16(x1 * cs - x2 * sn);
    q[base + 1] = __float2bfloat16(x1 * sn + x2 * cs);
    x1 = __bfloat162float(k[base]); x2 = __bfloat162float(k[base + 1]);
    k[base]     = __float2bfloat16(x1 * cs - x2 * sn);
    k[base + 1] = __float2bfloat16(x1 * sn + x2 * cs);
}

// ---------------------------------------------------------------------------
// MFMA flash attention (round-3 kernel, O now stored as bf16).
// ---------------------------------------------------------------------------
__global__ __launch_bounds__(256)
void attn_mfma(const __hip_bfloat16* __restrict__ qb,
               const __hip_bfloat16* __restrict__ kb,
               const __hip_bfloat16* __restrict__ vb,
               __hip_bfloat16* __restrict__ ob) {
    __shared__ ushort Ks[64][72];
    __shared__ ushort Vt[64][72];
    __shared__ float  Ps[4][16][68];

    const int bh   = blockIdx.y;
    const int qt   = blockIdx.x;
    const int tid  = threadIdx.x;
    const int w    = tid >> 6;
    const int lane = tid & 63;
    const int l16  = lane & 15;
    const int quad = lane >> 4;
    const size_t base = (size_t)bh * SEQ * DHEAD;

    const int qrow = qt * 64 + w * 16 + l16;
    bf16x8 qa[2];
    qa[0] = *reinterpret_cast<const bf16x8*>(qb + base + (size_t)qrow * DHEAD + quad * 8);
    qa[1] = *reinterpret_cast<const bf16x8*>(qb + base + (size_t)qrow * DHEAD + 32 + quad * 8);

    f32x4 oacc[4];
    #pragma unroll
    for (int s = 0; s < 4; s++) oacc[s] = (f32x4){0.f, 0.f, 0.f, 0.f};
    float mrow[4] = {-INFINITY, -INFINITY, -INFINITY, -INFINITY};
    float lrow[4] = {0.f, 0.f, 0.f, 0.f};

    const int key_s = tid & 63;
    const int dgrp  = tid >> 6;

    for (int t = 0; t <= qt; ++t) {
        __syncthreads();
        {
            const __hip_bfloat16* kp = kb + base + (size_t)(t * 64 + key_s) * DHEAD + dgrp * 16;
            const uint4 k0 = *reinterpret_cast<const uint4*>(kp);
            const uint4 k1 = *reinterpret_cast<const uint4*>(kp + 8);
            *reinterpret_cast<uint4*>(&Ks[key_s][dgrp * 16])     = k0;
            *reinterpret_cast<uint4*>(&Ks[key_s][dgrp * 16 + 8]) = k1;
            const __hip_bfloat16* vp = vb + base + (size_t)(t * 64 + key_s) * DHEAD + dgrp * 16;
            const uint4 v0 = *reinterpret_cast<const uint4*>(vp);
            const uint4 v1 = *reinterpret_cast<const uint4*>(vp + 8);
            const ushort* ve0 = reinterpret_cast<const ushort*>(&v0);
            const ushort* ve1 = reinterpret_cast<const ushort*>(&v1);
            #pragma unroll
            for (int i = 0; i < 8; i++) Vt[dgrp * 16 + i][key_s] = ve0[i];
            #pragma unroll
            for (int i = 0; i < 8; i++) Vt[dgrp * 16 + 8 + i][key_s] = ve1[i];
        }
        __syncthreads();

        f32x4 sacc[4];
        #pragma unroll
        for (int s = 0; s < 4; s++) sacc[s] = (f32x4){0.f, 0.f, 0.f, 0.f};
        #pragma unroll
        for (int half = 0; half < 2; half++) {
            #pragma unroll
            for (int sub = 0; sub < 4; sub++) {
                const bf16x8 bk = *reinterpret_cast<const bf16x8*>(
                    &Ks[sub * 16 + l16][half * 32 + quad * 8]);
                sacc[sub] = __builtin_amdgcn_mfma_f32_16x16x32_bf16(
                    qa[half], bk, sacc[sub], 0, 0, 0);
            }
        }

        const bool diag = (t == qt);
        float p[4][4];
        float tmax[4], tsum[4];
        #pragma unroll
        for (int r = 0; r < 4; r++) {
            float mx = -INFINITY;
            #pragma unroll
            for (int sub = 0; sub < 4; sub++) {
                float s = sacc[sub][r] * 0.125f;
                if (diag && (sub * 16 + l16 > w * 16 + quad * 4 + r)) s = -INFINITY;
                p[sub][r] = s;
                mx = fmaxf(mx, s);
            }
            tmax[r] = mx;
        }
        #pragma unroll
        for (int off = 1; off < 16; off <<= 1)
            #pragma unroll
            for (int r = 0; r < 4; r++)
                tmax[r] = fmaxf(tmax[r], __shfl_xor(tmax[r], off, 64));
        #pragma unroll
        for (int r = 0; r < 4; r++) {
            const float m_new = fmaxf(mrow[r], tmax[r]);
            const float alpha = __expf(mrow[r] - m_new);
            mrow[r] = m_new;
            float sum = 0.f;
            #pragma unroll
            for (int sub = 0; sub < 4; sub++) {
                const float e = __expf(p[sub][r] - m_new);
                p[sub][r] = e;
                sum += e;
            }
            tsum[r] = sum;
            lrow[r] *= alpha;
            #pragma unroll
            for (int sub = 0; sub < 4; sub++) oacc[sub][r] *= alpha;
        }
        #pragma unroll
        for (int off = 1; off < 16; off <<= 1)
            #pragma unroll
            for (int r = 0; r < 4; r++)
                tsum[r] += __shfl_xor(tsum[r], off, 64);
        #pragma unroll
        for (int r = 0; r < 4; r++) lrow[r] += tsum[r];

        #pragma unroll
        for (int sub = 0; sub < 4; sub++)
            #pragma unroll
            for (int r = 0; r < 4; r++)
                Ps[w][quad * 4 + r][sub * 16 + l16] = p[sub][r];
        bf16x8 pa[2];
        #pragma unroll
        for (int half = 0; half < 2; half++) {
            const float* pp = &Ps[w][l16][half * 32 + quad * 8];
            const f32x4 f0 = *reinterpret_cast<const f32x4*>(pp);
            const f32x4 f1 = *reinterpret_cast<const f32x4*>(pp + 4);
            bf16x8 tb;
            #pragma unroll
            for (int j = 0; j < 4; j++) {
                tb[j]     = (__bf16)f0[j];
                tb[4 + j] = (__bf16)f1[j];
            }
            pa[half] = tb;
        }

        #pragma unroll
        for (int half = 0; half < 2; half++) {
            #pragma unroll
            for (int sub = 0; sub < 4; sub++) {
                const bf16x8 bv = *reinterpret_cast<const bf16x8*>(
                    &Vt[sub * 16 + l16][half * 32 + quad * 8]);
                oacc[sub] = __builtin_amdgcn_mfma_f32_16x16x32_bf16(
                    pa[half], bv, oacc[sub], 0, 0, 0);
            }
        }
    }

    #pragma unroll
    for (int sub = 0; sub < 4; sub++) {
        #pragma unroll
        for (int r = 0; r < 4; r++) {
            const int q = qt * 64 + w * 16 + quad * 4 + r;
            ob[base + (size_t)q * DHEAD + sub * 16 + l16] =
                __float2bfloat16(oacc[sub][r] / lrow[r]);
        }
    }
}

// ---------------------------------------------------------------------------
extern "C" void kernel_launch(void* const* d_in, const int* in_sizes, int n_in,
                              void* d_out, int out_size, void* d_ws, size_t ws_size,
                              hipStream_t stream) {
    const float* x  = (const float*)d_in[0];
    const float* Wq = (const float*)d_in[1];
    const float* Wk = (const float*)d_in[2];
    const float* Wv = (const float*)d_in[3];
    const float* Wo = (const float*)d_in[4];
    const int* pos = (const int*)d_in[5];

    const size_t TEN = (size_t)MROWS * DMODEL;   // 4M elements
    const size_t WEL = (size_t)DMODEL * DMODEL;  // 1M elements
    ushort* xb  = (ushort*)d_ws;       // 8 MB
    ushort* Wqb = xb  + TEN;           // 2 MB
    ushort* Wkb = Wqb + WEL;
    ushort* Wvb = Wkb + WEL;
    ushort* Wob = Wvb + WEL;
    ushort* qb  = Wob + WEL;           // 8 MB each
    ushort* kb  = qb  + TEN;
    ushort* vb  = kb  + TEN;
    ushort* ob  = vb  + TEN;

    dim3 blk(256);
    cast_f32_bf16<<<TEN / (8 * 256), blk, 0, stream>>>(x,  xb,  (int)TEN);
    cast_f32_bf16<<<WEL / (8 * 256), blk, 0, stream>>>(Wq, Wqb, (int)WEL);
    cast_f32_bf16<<<WEL / (8 * 256), blk, 0, stream>>>(Wk, Wkb, (int)WEL);
    cast_f32_bf16<<<WEL / (8 * 256), blk, 0, stream>>>(Wv, Wvb, (int)WEL);
    cast_f32_bf16<<<WEL / (8 * 256), blk, 0, stream>>>(Wo, Wob, (int)WEL);

    dim3 ggemm(DMODEL / 128, MROWS / 128);   // (8, 32)
    gemm_bt<0, 0><<<ggemm, blk, 0, stream>>>(xb, Wqb, qb);
    gemm_bt<0, 0><<<ggemm, blk, 0, stream>>>(xb, Wkb, kb);
    gemm_bt<0, 0><<<ggemm, blk, 0, stream>>>(xb, Wvb, vb);

    const int npairs = BATCH * NHEAD * SEQ * (DHEAD / 2);
    rope_bf16<<<(npairs + 255) / 256, blk, 0, stream>>>(
        (__hip_bfloat16*)qb, (__hip_bfloat16*)kb, pos);

    dim3 gattn(SEQ / 64, BATCH * NHEAD);     // (32, 32)
    attn_mfma<<<gattn, blk, 0, stream>>>(
        (const __hip_bfloat16*)qb, (const __hip_bfloat16*)kb,
        (const __hip_bfloat16*)vb, (__hip_bfloat16*)ob);

    gemm_bt<1, 1><<<ggemm, blk, 0, stream>>>(ob, Wob, d_out);
}

// Round 5
// 271.502 us; speedup vs baseline: 9.7981x; 1.2094x over previous
//
#include <hip/hip_runtime.h>
#include <hip/hip_bf16.h>
#include <math.h>

#define DMODEL 1024
#define NHEAD  16
#define DHEAD  64
#define BATCH  2
#define SEQ    2048
#define MROWS  (BATCH * SEQ)   // 4096

typedef __attribute__((ext_vector_type(8))) __bf16 bf16x8;
typedef __attribute__((ext_vector_type(4))) float  f32x4;

// async global->LDS, 16 B per lane. LDS dest must be wave-uniform base + lane*16.
__device__ __forceinline__ void load16_lds(const ushort* g, ushort* l) {
    __builtin_amdgcn_global_load_lds(
        (const __attribute__((address_space(1))) unsigned int*)g,
        (__attribute__((address_space(3))) unsigned int*)l, 16, 0, 0);
}

// ---------------------------------------------------------------------------
// fp32 -> bf16 cast, 8 elem/thread
// ---------------------------------------------------------------------------
__global__ __launch_bounds__(256)
void cast_f32_bf16(const float* __restrict__ s, ushort* __restrict__ d, int n) {
    const int i = (blockIdx.x * 256 + threadIdx.x) * 8;
    if (i >= n) return;
    const f32x4 a = *reinterpret_cast<const f32x4*>(s + i);
    const f32x4 b = *reinterpret_cast<const f32x4*>(s + i + 4);
    bf16x8 o;
    #pragma unroll
    for (int j = 0; j < 4; j++) { o[j] = (__bf16)a[j]; o[4 + j] = (__bf16)b[j]; }
    *reinterpret_cast<bf16x8*>(d + i) = o;
}

// ---------------------------------------------------------------------------
// MFMA GEMM (m97 structure): C[m][n] = sum_k A[m][k] * B[n][k], bf16 in.
// 128x128 tile, BK=32, 4 waves each 64x64 (4x4 of 16x16x32), fp32 accum.
// AMODE 0: A row-major [M,DMODEL].  AMODE 1: A in [b,h,s,dh] (k=(h,dh)).
// OMODE 0: bf16 -> [b,h,s,dh].  OMODE 1: f32 row-major [M,DMODEL].
// OMODE 2: bf16 row-major [M][MROWS]  (used for V^T = Wv·X^T).
// ---------------------------------------------------------------------------
template <int AMODE, int OMODE>
__global__ __launch_bounds__(256)
void gemm_bt(const ushort* __restrict__ A, const ushort* __restrict__ B,
             void* __restrict__ C) {
    __shared__ __align__(16) ushort As[128 * 32];   // unpadded: global_load_lds order
    __shared__ __align__(16) ushort Bs[128 * 32];
    const int tid  = threadIdx.x;
    const int m0   = blockIdx.y * 128;
    const int n0   = blockIdx.x * 128;
    const int lane = tid & 63;
    const int w    = tid >> 6;
    const int l16  = lane & 15;
    const int quad = lane >> 4;
    const int wm   = (w >> 1) * 64;
    const int wn   = (w & 1) * 64;

    const int srow = tid >> 2;        // 0..63 (plus +64 second half)
    const int scol = (tid & 3) * 8;   // bf16 elem offset within K-tile

    f32x4 acc[4][4];
    #pragma unroll
    for (int i = 0; i < 4; i++)
        #pragma unroll
        for (int j = 0; j < 4; j++) acc[i][j] = (f32x4){0.f, 0.f, 0.f, 0.f};

    for (int k0 = 0; k0 < DMODEL; k0 += 32) {
        __syncthreads();   // previous iteration's ds_reads complete
        #pragma unroll
        for (int half = 0; half < 2; half++) {
            const int row = srow + half * 64;
            const ushort* ga;
            if (AMODE == 0) {
                ga = A + (size_t)(m0 + row) * DMODEL + k0 + scol;
            } else {
                const int m  = m0 + row;
                const int bb = m >> 11;
                const int ss = m & (SEQ - 1);
                const int kk = k0 + scol;
                const int h  = kk >> 6;
                const int dh = kk & 63;
                ga = A + (((size_t)(bb * NHEAD + h)) * SEQ + ss) * DHEAD + dh;
            }
            load16_lds(ga, &As[row * 32 + scol]);
            load16_lds(B + (size_t)(n0 + row) * DMODEL + k0 + scol,
                       &Bs[row * 32 + scol]);
        }
        __syncthreads();   // barrier drains vmcnt: tiles landed

        bf16x8 af[4], bfr[4];
        #pragma unroll
        for (int s = 0; s < 4; s++)
            af[s] = *reinterpret_cast<const bf16x8*>(
                &As[(wm + s * 16 + l16) * 32 + quad * 8]);
        #pragma unroll
        for (int s = 0; s < 4; s++)
            bfr[s] = *reinterpret_cast<const bf16x8*>(
                &Bs[(wn + s * 16 + l16) * 32 + quad * 8]);
        #pragma unroll
        for (int i = 0; i < 4; i++)
            #pragma unroll
            for (int j = 0; j < 4; j++)
                acc[i][j] = __builtin_amdgcn_mfma_f32_16x16x32_bf16(
                    af[i], bfr[j], acc[i][j], 0, 0, 0);
    }

    // epilogue: C/D layout row = quad*4 + r, col = l16
    if (OMODE == 0) {
        __hip_bfloat16* D = (__hip_bfloat16*)C;
        #pragma unroll
        for (int i = 0; i < 4; i++) {
            #pragma unroll
            for (int r = 0; r < 4; r++) {
                const int m  = m0 + wm + i * 16 + quad * 4 + r;
                const int bb = m >> 11;
                const int ss = m & (SEQ - 1);
                #pragma unroll
                for (int j = 0; j < 4; j++) {
                    const int n  = n0 + wn + j * 16 + l16;
                    const int h  = n >> 6;
                    const int dh = n & 63;
                    D[(((size_t)(bb * NHEAD + h)) * SEQ + ss) * DHEAD + dh] =
                        __float2bfloat16(acc[i][j][r]);
                }
            }
        }
    } else if (OMODE == 1) {
        float* D = (float*)C;
        #pragma unroll
        for (int i = 0; i < 4; i++)
            #pragma unroll
            for (int r = 0; r < 4; r++) {
                const int m = m0 + wm + i * 16 + quad * 4 + r;
                #pragma unroll
                for (int j = 0; j < 4; j++)
                    D[(size_t)m * DMODEL + n0 + wn + j * 16 + l16] = acc[i][j][r];
            }
    } else {
        ushort* D = (ushort*)C;
        #pragma unroll
        for (int i = 0; i < 4; i++)
            #pragma unroll
            for (int r = 0; r < 4; r++) {
                const int m = m0 + wm + i * 16 + quad * 4 + r;
                #pragma unroll
                for (int j = 0; j < 4; j++) {
                    __hip_bfloat16 hv = __float2bfloat16(acc[i][j][r]);
                    D[(size_t)m * MROWS + n0 + wn + j * 16 + l16] =
                        *reinterpret_cast<ushort*>(&hv);
                }
            }
    }
}

// ---------------------------------------------------------------------------
// RoPE in-place on bf16 q,k ([b,h,s,dh]).
// ---------------------------------------------------------------------------
__global__ __launch_bounds__(256)
void rope_bf16(__hip_bfloat16* __restrict__ q, __hip_bfloat16* __restrict__ k,
               const int* __restrict__ pos) {
    const int idx = blockIdx.x * blockDim.x + threadIdx.x;
    const int total = BATCH * NHEAD * SEQ * (DHEAD / 2);
    if (idx >= total) return;
    const int i  = idx & 31;
    const int s  = (idx >> 5) & (SEQ - 1);
    const int bh = idx >> 16;
    const float p = (float)pos[s];
    const float freq = p * powf(10000.0f, -(float)(2 * i) / (float)DHEAD);
    float sn, cs;
    sincosf(freq, &sn, &cs);
    const size_t base = (((size_t)bh * SEQ + s) * DHEAD) + 2 * i;
    float x1 = __bfloat162float(q[base]), x2 = __bfloat162float(q[base + 1]);
    q[base]     = __float2bfloat16(x1 * cs - x2 * sn);
    q[base + 1] = __float2bfloat16(x1 * sn + x2 * cs);
    x1 = __bfloat162float(k[base]); x2 = __bfloat162float(k[base + 1]);
    k[base]     = __float2bfloat16(x1 * cs - x2 * sn);
    k[base + 1] = __float2bfloat16(x1 * sn + x2 * cs);
}

// ---------------------------------------------------------------------------
// MFMA flash attention v2.
//  - S^T formulation: QK^T computed as mfma(A=K, B=Q) -> row=key, col=q.
//    Per lane: one q (=l16), 16 key values -> local max/sum + 2 shuffles.
//  - V^T comes pre-transposed from global ([feature][token]), staged b128.
//  - P stored to LDS as bf16 (b64 packs), read back as A-frags (b128).
//  - qt reversed for load balance; diagonal tile skips masked MFMAs.
// ---------------------------------------------------------------------------
__global__ __launch_bounds__(256)
void attn_mfma2(const ushort* __restrict__ qb, const ushort* __restrict__ kb,
                const ushort* __restrict__ vtg, ushort* __restrict__ ob) {
    __shared__ ushort Ks[64][72];      // [key][d]
    __shared__ ushort Vs[64][72];      // [d][key]
    __shared__ ushort Pb[4][16][72];   // per-wave [q][key] bf16

    const int bh   = blockIdx.y;
    const int b    = bh >> 4;
    const int h    = bh & 15;
    const int qt   = (gridDim.x - 1) - blockIdx.x;   // heavy blocks first
    const int tid  = threadIdx.x;
    const int w    = tid >> 6;
    const int lane = tid & 63;
    const int l16  = lane & 15;
    const int quad = lane >> 4;
    const size_t base = (size_t)bh * SEQ * DHEAD;

    // Q fragments (B operand), pre-scaled by 1/sqrt(64) (exact in bf16)
    const int qrow = qt * 64 + w * 16 + l16;
    bf16x8 qa[2];
    qa[0] = *reinterpret_cast<const bf16x8*>(qb + base + (size_t)qrow * DHEAD + quad * 8);
    qa[1] = *reinterpret_cast<const bf16x8*>(qb + base + (size_t)qrow * DHEAD + 32 + quad * 8);
    #pragma unroll
    for (int j = 0; j < 8; j++) {
        qa[0][j] = (__bf16)(0.125f * (float)qa[0][j]);
        qa[1][j] = (__bf16)(0.125f * (float)qa[1][j]);
    }

    f32x4 oacc[4];
    #pragma unroll
    for (int s = 0; s < 4; s++) oacc[s] = (f32x4){0.f, 0.f, 0.f, 0.f};
    float m_ = -INFINITY, l_ = 0.f;

    const int srow = tid >> 2;        // staging row 0..63
    const int scol = (tid & 3) * 16;  // 16 ushorts per chunk
    const ushort* vbase = vtg + (size_t)(h * DHEAD + srow) * MROWS + b * SEQ + scol;
    const ushort* kbase = kb + base + (size_t)srow * DHEAD + scol;

    for (int t = 0; t <= qt; ++t) {
        __syncthreads();   // previous tile's LDS reads complete
        {
            const ushort* kp = kbase + (size_t)t * 64 * DHEAD;
            *reinterpret_cast<uint4*>(&Ks[srow][scol])     = *reinterpret_cast<const uint4*>(kp);
            *reinterpret_cast<uint4*>(&Ks[srow][scol + 8]) = *reinterpret_cast<const uint4*>(kp + 8);
            const ushort* vp = vbase + t * 64;
            *reinterpret_cast<uint4*>(&Vs[srow][scol])     = *reinterpret_cast<const uint4*>(vp);
            *reinterpret_cast<uint4*>(&Vs[srow][scol + 8]) = *reinterpret_cast<const uint4*>(vp + 8);
        }
        __syncthreads();

        const bool diag  = (t == qt);
        const int  nsub  = diag ? (w + 1) : 4;        // wave-uniform
        const int  nhalf = diag ? ((w >> 1) + 1) : 2; // wave-uniform

        // ---- S^T = (K Q^T): rows=keys, cols=q ----
        f32x4 sacc[4];
        #pragma unroll
        for (int s = 0; s < 4; s++) sacc[s] = (f32x4){0.f, 0.f, 0.f, 0.f};
        #pragma unroll
        for (int half = 0; half < 2; half++)
            #pragma unroll
            for (int sub = 0; sub < 4; sub++)
                if (sub < nsub) {
                    const bf16x8 ka = *reinterpret_cast<const bf16x8*>(
                        &Ks[sub * 16 + l16][half * 32 + quad * 8]);
                    sacc[sub] = __builtin_amdgcn_mfma_f32_16x16x32_bf16(
                        ka, qa[half], sacc[sub], 0, 0, 0);
                }

        // ---- online softmax (per-lane: q = l16, keys = sub*16+quad*4+r) ----
        float sv[4][4];
        #pragma unroll
        for (int sub = 0; sub < 4; sub++)
            #pragma unroll
            for (int r = 0; r < 4; r++) sv[sub][r] = sacc[sub][r];
        if (diag) {
            #pragma unroll
            for (int sub = 0; sub < 4; sub++)
                #pragma unroll
                for (int r = 0; r < 4; r++)
                    if (sub * 16 + quad * 4 + r > w * 16 + l16)
                        sv[sub][r] = -INFINITY;
        }
        float mx = sv[0][0];
        #pragma unroll
        for (int sub = 0; sub < 4; sub++)
            #pragma unroll
            for (int r = 0; r < 4; r++) mx = fmaxf(mx, sv[sub][r]);
        mx = fmaxf(mx, __shfl_xor(mx, 16, 64));
        mx = fmaxf(mx, __shfl_xor(mx, 32, 64));
        const float mnew  = fmaxf(m_, mx);
        const float alpha = __expf(m_ - mnew);   // 0 on first tile
        m_ = mnew;

        float sum = 0.f;
        float ev[4][4];
        #pragma unroll
        for (int sub = 0; sub < 4; sub++)
            #pragma unroll
            for (int r = 0; r < 4; r++) {
                const float e = __expf(sv[sub][r] - mnew);
                ev[sub][r] = e;
                sum += e;
            }
        sum += __shfl_xor(sum, 16, 64);
        sum += __shfl_xor(sum, 32, 64);
        l_ = l_ * alpha + sum;

        // rescale O: row r of O-tile needs alpha of q = quad*4+r
        float ar[4];
        #pragma unroll
        for (int r = 0; r < 4; r++) ar[r] = __shfl(alpha, quad * 4 + r, 64);
        #pragma unroll
        for (int sub = 0; sub < 4; sub++)
            #pragma unroll
            for (int r = 0; r < 4; r++) oacc[sub][r] *= ar[r];

        // ---- P -> LDS (bf16, b64 packs), wave-private ----
        #pragma unroll
        for (int sub = 0; sub < 4; sub++) {
            ushort4 pk;
            __hip_bfloat16 h0 = __float2bfloat16(ev[sub][0]);
            __hip_bfloat16 h1 = __float2bfloat16(ev[sub][1]);
            __hip_bfloat16 h2 = __float2bfloat16(ev[sub][2]);
            __hip_bfloat16 h3 = __float2bfloat16(ev[sub][3]);
            pk.x = *reinterpret_cast<ushort*>(&h0);
            pk.y = *reinterpret_cast<ushort*>(&h1);
            pk.z = *reinterpret_cast<ushort*>(&h2);
            pk.w = *reinterpret_cast<ushort*>(&h3);
            *reinterpret_cast<ushort4*>(&Pb[w][l16][sub * 16 + quad * 4]) = pk;
        }
        bf16x8 pa[2];
        pa[0] = *reinterpret_cast<const bf16x8*>(&Pb[w][l16][quad * 8]);
        pa[1] = *reinterpret_cast<const bf16x8*>(&Pb[w][l16][32 + quad * 8]);

        // ---- O += P V ----
        #pragma unroll
        for (int half = 0; half < 2; half++)
            if (half < nhalf)
                #pragma unroll
                for (int sub = 0; sub < 4; sub++) {
                    const bf16x8 vv = *reinterpret_cast<const bf16x8*>(
                        &Vs[sub * 16 + l16][half * 32 + quad * 8]);
                    oacc[sub] = __builtin_amdgcn_mfma_f32_16x16x32_bf16(
                        pa[half], vv, oacc[sub], 0, 0, 0);
                }
    }

    // epilogue: O rows q=quad*4+r need l of that q
    float inv[4];
    #pragma unroll
    for (int r = 0; r < 4; r++) inv[r] = 1.f / __shfl(l_, quad * 4 + r, 64);
    #pragma unroll
    for (int sub = 0; sub < 4; sub++)
        #pragma unroll
        for (int r = 0; r < 4; r++) {
            const int q = qt * 64 + w * 16 + quad * 4 + r;
            __hip_bfloat16 hv = __float2bfloat16(oacc[sub][r] * inv[r]);
            ob[base + (size_t)q * DHEAD + sub * 16 + l16] =
                *reinterpret_cast<ushort*>(&hv);
        }
}

// ---------------------------------------------------------------------------
extern "C" void kernel_launch(void* const* d_in, const int* in_sizes, int n_in,
                              void* d_out, int out_size, void* d_ws, size_t ws_size,
                              hipStream_t stream) {
    const float* x  = (const float*)d_in[0];
    const float* Wq = (const float*)d_in[1];
    const float* Wk = (const float*)d_in[2];
    const float* Wv = (const float*)d_in[3];
    const float* Wo = (const float*)d_in[4];
    const int* pos = (const int*)d_in[5];

    const size_t TEN = (size_t)MROWS * DMODEL;   // 4M elements
    const size_t WEL = (size_t)DMODEL * DMODEL;  // 1M elements
    ushort* xb  = (ushort*)d_ws;       // 8 MB
    ushort* Wqb = xb  + TEN;           // 2 MB each
    ushort* Wkb = Wqb + WEL;
    ushort* Wvb = Wkb + WEL;
    ushort* Wob = Wvb + WEL;
    ushort* qb  = Wob + WEL;           // 8 MB each
    ushort* kb  = qb  + TEN;
    ushort* vtb = kb  + TEN;           // V^T [1024][4096]
    ushort* ob  = vtb + TEN;

    dim3 blk(256);
    cast_f32_bf16<<<TEN / (8 * 256), blk, 0, stream>>>(x,  xb,  (int)TEN);
    cast_f32_bf16<<<WEL / (8 * 256), blk, 0, stream>>>(Wq, Wqb, (int)WEL);
    cast_f32_bf16<<<WEL / (8 * 256), blk, 0, stream>>>(Wk, Wkb, (int)WEL);
    cast_f32_bf16<<<WEL / (8 * 256), blk, 0, stream>>>(Wv, Wvb, (int)WEL);
    cast_f32_bf16<<<WEL / (8 * 256), blk, 0, stream>>>(Wo, Wob, (int)WEL);

    dim3 ggemm(DMODEL / 128, MROWS / 128);   // (8, 32)
    gemm_bt<0, 0><<<ggemm, blk, 0, stream>>>(xb, Wqb, qb);
    gemm_bt<0, 0><<<ggemm, blk, 0, stream>>>(xb, Wkb, kb);
    // V^T = Wv · X^T : A=Wv (M=1024), B=X (N=4096) -> [feature][token]
    dim3 gvt(MROWS / 128, DMODEL / 128);     // (32, 8)
    gemm_bt<0, 2><<<gvt, blk, 0, stream>>>(Wvb, xb, vtb);

    const int npairs = BATCH * NHEAD * SEQ * (DHEAD / 2);
    rope_bf16<<<(npairs + 255) / 256, blk, 0, stream>>>(
        (__hip_bfloat16*)qb, (__hip_bfloat16*)kb, pos);

    dim3 gattn(SEQ / 64, BATCH * NHEAD);     // (32, 32)
    attn_mfma2<<<gattn, blk, 0, stream>>>(qb, kb, vtb, ob);

    gemm_bt<1, 1><<<ggemm, blk, 0, stream>>>(ob, Wob, d_out);
}